// Round 13
// baseline (441.196 us; speedup 1.0000x reference)
//
#include <hip/hip_runtime.h>
#include <hip/hip_bf16.h>

// Problem: B=16, N=4096, C=768, H=12, D=64
// out = gelu(x@Wq) @ [ gelu( (Wk^T (x^T x) Wv) * SCALE ) @ Wp_h ] + b
// via G_b = x_b^T x_b (symmetric) ; T_b = G_b @ Wv ; kv_h = Wk_h^T T_h

typedef __attribute__((ext_vector_type(8))) short short8_t;
typedef __attribute__((ext_vector_type(4))) float f32x4_t;

typedef __attribute__((address_space(1))) void as1_void;
typedef __attribute__((address_space(3))) void as3_void;

__device__ __forceinline__ void gload_lds16(const void* g, void* l) {
    __builtin_amdgcn_global_load_lds(
        (as1_void*)(unsigned long long)(g),
        (as3_void*)(unsigned long long)(l), 16, 0, 0);
}

// fast gelu (tanh form, branchless); |err| < ~1e-3 vs erf-gelu, below bf16 rounding.
__device__ __forceinline__ float gelu_f(float x) {
    float x2 = x * x;
    float t = x * fmaf(0.0356774081f, x2, 0.7978845608f);
    float e = __expf(2.0f * t);
    float th = 1.0f - 2.0f / (e + 1.0f);
    return 0.5f * x * (1.0f + th);
}

__device__ __forceinline__ unsigned short to_bf16(float f) {
    __hip_bfloat16 h = __float2bfloat16(f);
    return *reinterpret_cast<unsigned short*>(&h);
}

__device__ __forceinline__ f32x4_t mfma16(short8_t a, short8_t b, f32x4_t c) {
    return __builtin_amdgcn_mfma_f32_16x16x32_bf16(a, b, c, 0, 0, 0);
}

// ---------------- f32 -> bf16 convert (x) ----------------
__global__ __launch_bounds__(256) void k_cvt_bf16(const float* __restrict__ in,
                                                  unsigned short* __restrict__ out,
                                                  long n) {
    long i = (long)blockIdx.x * blockDim.x + threadIdx.x;
    long stride = (long)gridDim.x * blockDim.x;
    for (long idx = i * 4; idx < n; idx += stride * 4) {
        float4 v = *(const float4*)(in + idx);
        ushort4 o;
        o.x = to_bf16(v.x); o.y = to_bf16(v.y); o.z = to_bf16(v.z); o.w = to_bf16(v.w);
        *(ushort4*)(out + idx) = o;
    }
}

// ---------------- merged weight prep: wqkvT / wprojT / wqkv_bf ----------------
__global__ __launch_bounds__(256) void k_wprep(const float* __restrict__ w_qkv,
                                               const float* __restrict__ w_proj,
                                               unsigned short* __restrict__ wqkvT,
                                               unsigned short* __restrict__ wpT,
                                               unsigned short* __restrict__ wqkv_bf) {
    const int blk = blockIdx.x, tid = threadIdx.x;
    if (blk < 864) {
        int gid = blk * 256 + tid;                 // 2304*96
        int c = gid / 96, r0 = (gid % 96) * 8;
        short8_t o;
#pragma unroll
        for (int i = 0; i < 8; ++i)
            o[i] = (short)to_bf16(w_qkv[(size_t)(r0 + i) * 2304 + c]);
        *(short8_t*)(wqkvT + (size_t)c * 768 + r0) = o;
    } else if (blk < 1152) {
        int gid = (blk - 864) * 256 + tid;         // 768*96
        int c = gid / 96, r0 = (gid % 96) * 8;
        short8_t o;
#pragma unroll
        for (int i = 0; i < 8; ++i)
            o[i] = (short)to_bf16(w_proj[(size_t)(r0 + i) * 768 + c]);
        *(short8_t*)(wpT + (size_t)c * 768 + r0) = o;
    } else {
        long i = (long)(blk - 1152) * 256 + tid;
        long stride = 432L * 256;
        for (long idx = i * 4; idx < 1769472L; idx += stride * 4) {
            float4 v = *(const float4*)(w_qkv + idx);
            ushort4 o;
            o.x = to_bf16(v.x); o.y = to_bf16(v.y); o.z = to_bf16(v.z); o.w = to_bf16(v.w);
            *(ushort4*)(wqkv_bf + idx) = o;
        }
    }
}

// ================= 128x128 GEMM: 4 waves, 32KB LDS, ~5 blocks/CU (TLP) =================
// Swizzled gload_lds staging (pre-swizzled global source) + conflict-free b128 frag reads.
template<bool GELU_EPI, bool BATCHED_B, bool BF16_OUT, bool BIAS>
__global__ __launch_bounds__(256)
void k_gemm128(const unsigned short* __restrict__ A, int lda,
               const unsigned short* __restrict__ Bt, int ldb,
               void* __restrict__ Cout, int ldc,
               const float* __restrict__ bias,
               int tiles_n, int K) {
    __shared__ __attribute__((aligned(16))) unsigned short As[128 * 64];
    __shared__ __attribute__((aligned(16))) unsigned short Bs[128 * 64];

    const int nwg = gridDim.x;
    int bid = blockIdx.x;
    bid = (bid & 7) * (nwg >> 3) + (bid >> 3);   // nwg % 8 == 0

    const int tn = bid % tiles_n, tm = bid / tiles_n;
    const int row0 = tm * 128, col0 = tn * 128;

    const unsigned short* Bb = Bt;
    if (BATCHED_B) Bb += (size_t)(row0 >> 12) * 768 * 768;

    const int tid = threadIdx.x, lane = tid & 63, w = tid >> 6;
    const int wm = w >> 1, wn = w & 1;
    const int lr = lane & 15, lg = lane >> 4;

    f32x4_t acc[4][4] = {};

    const int nt = K >> 6;
    for (int kt = 0; kt < nt; ++kt) {
        // stage A,B tiles [128][64]: 1024 chunks each, 4 per thread per matrix
#pragma unroll
        for (int i = 0; i < 4; ++i) {
            int ch = i * 256 + tid;
            int sr = ch >> 3, sk = (ch & 7) ^ (sr & 7);
            gload_lds16(A + (size_t)(row0 + sr) * lda + kt * 64 + sk * 8, As + ch * 8);
            gload_lds16(Bb + (size_t)(col0 + sr) * ldb + kt * 64 + sk * 8, Bs + ch * 8);
        }
        __syncthreads();
#pragma unroll
        for (int ks = 0; ks < 2; ++ks) {
            short8_t a[4], b[4];
#pragma unroll
            for (int mi = 0; mi < 4; ++mi) {
                int row = wm * 64 + mi * 16 + lr;
                a[mi] = *(const short8_t*)(As + row * 64 + (((ks * 4 + lg) ^ (row & 7)) << 3));
            }
#pragma unroll
            for (int nj = 0; nj < 4; ++nj) {
                int row = wn * 64 + nj * 16 + lr;
                b[nj] = *(const short8_t*)(Bs + row * 64 + (((ks * 4 + lg) ^ (row & 7)) << 3));
            }
#pragma unroll
            for (int mi = 0; mi < 4; ++mi)
#pragma unroll
                for (int nj = 0; nj < 4; ++nj)
                    acc[mi][nj] = mfma16(a[mi], b[nj], acc[mi][nj]);
        }
        __syncthreads();
    }

    const int rbase = row0 + wm * 64 + (lg << 2);
    const int cbase = col0 + wn * 64 + lr;
#pragma unroll
    for (int mi = 0; mi < 4; ++mi)
#pragma unroll
        for (int nj = 0; nj < 4; ++nj)
#pragma unroll
            for (int r = 0; r < 4; ++r) {
                int row = rbase + mi * 16 + r;
                int col = cbase + nj * 16;
                float v = acc[mi][nj][r];
                if (GELU_EPI) v = gelu_f(v);
                if (BIAS) v += bias[col];
                if (BF16_OUT)
                    ((unsigned short*)Cout)[(size_t)row * ldc + col] = to_bf16(v);
                else
                    ((float*)Cout)[(size_t)row * ldc + col] = v;
            }
}

// ---------------- G_b = x_b^T x_b : symmetric, 21 upper 128x128 tiles ----------------
__global__ __launch_bounds__(256) void k_G(const unsigned short* __restrict__ xb,
                                           unsigned short* __restrict__ Gst) {
    static const signed char TI[21] = {0,0,0,0,0,0,1,1,1,1,1,2,2,2,2,3,3,3,4,4,5};
    static const signed char TJ[21] = {0,1,2,3,4,5,1,2,3,4,5,2,3,4,5,3,4,5,4,5,5};
    int bid = blockIdx.x;
    bid = (bid & 7) * 42 + (bid >> 3);            // 336 = 8*42, bijective
    const int b = bid / 21, t = bid % 21;
    const int d0 = TI[t] * 128, e0 = TJ[t] * 128;
    const bool diag = (d0 == e0);
    const unsigned short* xB = xb + (size_t)b * 4096 * 768;

    __shared__ __attribute__((aligned(16))) unsigned short lds[2][2][128 * 64];

    const int tid = threadIdx.x, lane = tid & 63, w = tid >> 6;
    const int colg = tid & 15;
    const int rq8 = (tid >> 4) & 7;
    const int blk = tid >> 7;
    const int wm = w >> 1, wn = w & 1;
    const int lr = lane & 15, lg = lane >> 4;
    const int base0 = (blk ? e0 : d0) + colg * 8;
    const int tb = diag ? 0 : 1;
    const bool active = (!diag) || (blk == 0);

    f32x4_t acc[4][4] = {};
    short8_t ra[8];

    auto loadx = [&](int it) {
        if (!active) return;
        const size_t rbase = (size_t)(it * 64 + rq8 * 8) * 768 + base0;
#pragma unroll
        for (int rr = 0; rr < 8; ++rr)
            ra[rr] = *(const short8_t*)(xB + rbase + (size_t)rr * 768);
    };
    auto writes = [&](int buf) {
        if (!active) return;
#pragma unroll
        for (int j = 0; j < 8; ++j) {
            const int c = colg * 8 + j;
            const int sw3 = ((c & 7) ^ (c >> 3)) & 7;
            short8_t v;
#pragma unroll
            for (int rr = 0; rr < 8; ++rr) v[rr] = ra[rr][j];
            *(short8_t*)(&lds[buf][blk][c * 64 + ((rq8 ^ sw3) << 3)]) = v;
        }
    };
    auto ldfrag = [&](int buf, int tile, int cbase, int o) -> short8_t {
        const int c = cbase + lr;
        const int sw3 = ((c & 7) ^ (c >> 3)) & 7;
        return *(const short8_t*)(&lds[buf][tile][c * 64 + ((o ^ sw3) << 3)]);
    };

    loadx(0);
    writes(0);
    __syncthreads();

    for (int it = 0; it < 64; ++it) {
        const int buf = it & 1;
        if (it < 63) loadx(it + 1);
#pragma unroll
        for (int ks = 0; ks < 2; ++ks) {
            short8_t af[4], bf[4];
#pragma unroll
            for (int mi = 0; mi < 4; ++mi)
                af[mi] = ldfrag(buf, 0, wm * 64 + mi * 16, ks * 4 + lg);
#pragma unroll
            for (int nj = 0; nj < 4; ++nj)
                bf[nj] = ldfrag(buf, tb, wn * 64 + nj * 16, ks * 4 + lg);
#pragma unroll
            for (int mi = 0; mi < 4; ++mi)
#pragma unroll
                for (int nj = 0; nj < 4; ++nj)
                    acc[mi][nj] = mfma16(af[mi], bf[nj], acc[mi][nj]);
        }
        if (it < 63) writes(buf ^ 1);
        __syncthreads();
    }

    const int dbase = d0 + wm * 64 + (lg << 2);
    const int ebase = e0 + wn * 64 + lr;
#pragma unroll
    for (int mi = 0; mi < 4; ++mi)
#pragma unroll
        for (int nj = 0; nj < 4; ++nj)
#pragma unroll
            for (int r = 0; r < 4; ++r)
                Gst[((size_t)b * 768 + dbase + mi * 16 + r) * 768 + ebase + nj * 16] =
                    to_bf16(acc[mi][nj][r]);

    if (!diag) {
        unsigned short* T = &lds[0][0][0];
#pragma unroll
        for (int mi = 0; mi < 4; ++mi)
#pragma unroll
            for (int nj = 0; nj < 4; ++nj) {
                const int el = wn * 64 + nj * 16 + lr;
                const int sig = ((el ^ (el >> 3)) & 7) << 1;
                const int s = wm * 16 + mi * 4 + lg;
                uint2 pk;
                pk.x = (unsigned int)to_bf16(acc[mi][nj][0]) |
                       ((unsigned int)to_bf16(acc[mi][nj][1]) << 16);
                pk.y = (unsigned int)to_bf16(acc[mi][nj][2]) |
                       ((unsigned int)to_bf16(acc[mi][nj][3]) << 16);
                *(uint2*)(&T[el * 128 + ((s ^ sig) << 2)]) = pk;
            }
        __syncthreads();
#pragma unroll
        for (int i = 0; i < 8; ++i) {
            const int el = i * 16 + (tid >> 4);
            const int p = tid & 15;
            const int sig = ((el ^ (el >> 3)) & 7) << 1;
            short8_t v = *(const short8_t*)(&T[el * 128 + (((2 * p) ^ sig) << 2)]);
            *(short8_t*)(Gst + ((size_t)b * 768 + e0 + el) * 768 + d0 + p * 8) = v;
        }
    }
}

// ---------------- merged: kv_h = Wk_h^T T_h (scale+gelu) then M-tiles -> MT ----------------
__global__ __launch_bounds__(256) void k_kvM(const unsigned short* __restrict__ wqkv_bf,
                                             const unsigned short* __restrict__ Tst,
                                             const unsigned short* __restrict__ wpT,
                                             unsigned short* __restrict__ MT) {
    const int bh = blockIdx.x;
    const int b = bh / 12, h = bh % 12;
    const unsigned short* kptr = wqkv_bf + 768 + h * 64;
    const unsigned short* vptr = Tst + (size_t)b * 768 * 768 + h * 64;

    __shared__ __attribute__((aligned(16))) unsigned short kT[64 * 64];
    __shared__ __attribute__((aligned(16))) unsigned short vT[64 * 64];
    __shared__ __attribute__((aligned(16))) unsigned short As[64 * 64];
    __shared__ __attribute__((aligned(16))) unsigned short Bs[256 * 64];

    const int tid = threadIdx.x, lane = tid & 63, w = tid >> 6;
    const int np = tid >> 3;
    const int g = tid & 7;
    const int lr = lane & 15, lg = lane >> 4;

    f32x4_t acc[4] = {};

    for (int it = 0; it < 12; ++it) {
        const size_t r = (size_t)(it * 64 + 2 * np);
        short8_t k0 = *(const short8_t*)(kptr + r * 2304 + g * 8);
        short8_t k1 = *(const short8_t*)(kptr + (r + 1) * 2304 + g * 8);
        short8_t v0 = *(const short8_t*)(vptr + r * 768 + g * 8);
        short8_t v1 = *(const short8_t*)(vptr + (r + 1) * 768 + g * 8);
        __syncthreads();
#pragma unroll
        for (int j = 0; j < 8; ++j) {
            const int d = g * 8 + j;
            const int e = d * 64 + ((2 * np) ^ (((d ^ (d >> 3)) & 7) << 3));
            *(unsigned int*)(kT + e) =
                (unsigned int)(unsigned short)k0[j] | ((unsigned int)(unsigned short)k1[j] << 16);
            *(unsigned int*)(vT + e) =
                (unsigned int)(unsigned short)v0[j] | ((unsigned int)(unsigned short)v1[j] << 16);
        }
        __syncthreads();
#pragma unroll
        for (int ks = 0; ks < 2; ++ks) {
            const int d = w * 16 + lr;
            short8_t a = *(const short8_t*)(kT + d * 64 +
                (((ks * 4 + lg) ^ ((d ^ (d >> 3)) & 7)) << 3));
#pragma unroll
            for (int nj = 0; nj < 4; ++nj) {
                const int e2 = nj * 16 + lr;
                short8_t bf = *(const short8_t*)(vT + e2 * 64 +
                    (((ks * 4 + lg) ^ ((e2 ^ (e2 >> 3)) & 7)) << 3));
                acc[nj] = __builtin_amdgcn_mfma_f32_16x16x32_bf16(a, bf, acc[nj], 0, 0, 0);
            }
        }
    }

    // gelu'd kv -> As [d:64][e:64] bf16, 8-chunk swizzled: chunk' = (e>>3) ^ (d&7)
    {
        const int drow = w * 16 + (lg << 2);
#pragma unroll
        for (int nj = 0; nj < 4; ++nj)
#pragma unroll
            for (int r = 0; r < 4; ++r) {
                const int d = drow + r;
                const int e = nj * 16 + lr;
                As[d * 64 + ((((e >> 3) ^ (d & 7)) << 3) | (e & 7))] =
                    to_bf16(gelu_f(acc[nj][r] * 0.125f));
            }
    }

    for (int ct = 0; ct < 3; ++ct) {
        const int c0 = ct * 256;
        short8_t rb[8];
#pragma unroll
        for (int i = 0; i < 8; ++i) {
            int ch = i * 256 + tid, row = ch >> 3, kc = ch & 7;
            rb[i] = *(const short8_t*)(wpT + (size_t)(c0 + row) * 768 + h * 64 + kc * 8);
        }
        __syncthreads();
#pragma unroll
        for (int i = 0; i < 8; ++i) {
            int ch = i * 256 + tid, row = ch >> 3, kc = ch & 7;
            *(short8_t*)(Bs + row * 64 + ((kc ^ (row & 7)) * 8)) = rb[i];
        }
        __syncthreads();

        f32x4_t acc2[4][4] = {};
#pragma unroll
        for (int ks = 0; ks < 2; ++ks) {
            short8_t a[4], bfr[4];
#pragma unroll
            for (int mi = 0; mi < 4; ++mi) {
                int row = mi * 16 + lr;
                a[mi] = *(const short8_t*)(As + row * 64 + (((ks * 4 + lg) ^ (row & 7)) * 8));
            }
#pragma unroll
            for (int nj = 0; nj < 4; ++nj) {
                int row = w * 64 + nj * 16 + lr;
                bfr[nj] = *(const short8_t*)(Bs + row * 64 + (((ks * 4 + lg) ^ (row & 7)) * 8));
            }
#pragma unroll
            for (int mi = 0; mi < 4; ++mi)
#pragma unroll
                for (int nj = 0; nj < 4; ++nj)
                    acc2[mi][nj] = __builtin_amdgcn_mfma_f32_16x16x32_bf16(a[mi], bfr[nj], acc2[mi][nj], 0, 0, 0);
        }
        __syncthreads();

#pragma unroll
        for (int mi = 0; mi < 4; ++mi)
#pragma unroll
            for (int nj = 0; nj < 4; ++nj) {
                unsigned int w0 = (unsigned int)to_bf16(acc2[mi][nj][0]) |
                                  ((unsigned int)to_bf16(acc2[mi][nj][1]) << 16);
                unsigned int w1 = (unsigned int)to_bf16(acc2[mi][nj][2]) |
                                  ((unsigned int)to_bf16(acc2[mi][nj][3]) << 16);
                uint2 pk; pk.x = w0; pk.y = w1;
                *(uint2*)(Bs + (w * 64 + nj * 16 + lr) * 64 + mi * 16 + lg * 4) = pk;
            }
        __syncthreads();
#pragma unroll
        for (int i = 0; i < 8; ++i) {
            int ch = i * 256 + tid, cl = ch >> 3, dk = ch & 7;
            short8_t v = *(const short8_t*)(Bs + cl * 64 + dk * 8);
            *(short8_t*)(MT + ((size_t)(b * 768) + c0 + cl) * 768 + h * 64 + dk * 8) = v;
        }
    }
}

extern "C" void kernel_launch(void* const* d_in, const int* in_sizes, int n_in,
                              void* d_out, int out_size, void* d_ws, size_t ws_size,
                              hipStream_t stream) {
    const float* x      = (const float*)d_in[0];
    const float* w_qkv  = (const float*)d_in[1];
    const float* w_proj = (const float*)d_in[2];
    const float* b_proj = (const float*)d_in[3];
    float* out = (float*)d_out;
    char* ws = (char*)d_ws;

    unsigned short* q_gelu  = (unsigned short*)(ws);               // 100,663,296
    unsigned short* wqkvT   = (unsigned short*)(ws + 100663296);   //   3,538,944
    unsigned short* wqkv_bf = (unsigned short*)(ws + 104202240);   //   3,538,944
    unsigned short* G_bf    = (unsigned short*)(ws + 107741184);   //  18,874,368
    unsigned short* T_bf    = (unsigned short*)(ws + 126615552);   //  18,874,368
    unsigned short* MT      = (unsigned short*)(ws + 145489920);   //  18,874,368
    unsigned short* xb   = (unsigned short*)d_out;                 // scratch in d_out
    unsigned short* wpT  = (unsigned short*)((char*)d_out + 136314880);

    k_cvt_bf16<<<2048, 256, 0, stream>>>(x, xb, 50331648L);
    k_wprep<<<1584, 256, 0, stream>>>(w_qkv, w_proj, wqkvT, wpT, wqkv_bf);
    // GEMM1q: q_gelu = gelu(xb @ Wq^T)  [65536,768], 512x6 = 3072 tiles
    k_gemm128<true, false, true, false><<<3072, 256, 0, stream>>>(
        xb, 768, wqkvT, 768, q_gelu, 768, nullptr, 6, 768);
    // G_b = x_b^T x_b (symmetric, 21 upper tiles per batch)
    k_G<<<336, 256, 0, stream>>>(xb, G_bf);
    // T_b = G_b @ Wv
    k_gemm128<false, false, true, false><<<576, 256, 0, stream>>>(
        G_bf, 768, wqkvT + (size_t)1536 * 768, 768, T_bf, 768, nullptr, 6, 768);
    // kv_h + M fold
    k_kvM<<<192, 256, 0, stream>>>(wqkv_bf, T_bf, wpT, MT);
    // GEMM2: out = q_gelu @ MT_b^T + b_proj (batched B, f32 out)
    k_gemm128<false, true, false, true><<<3072, 256, 0, stream>>>(
        q_gelu, 768, MT, 768, out, 768, b_proj, 6, 768);
}

// Round 14
// 389.080 us; speedup vs baseline: 1.1339x; 1.1339x over previous
//
#include <hip/hip_runtime.h>
#include <hip/hip_bf16.h>

// Problem: B=16, N=4096, C=768, H=12, D=64
// out = gelu(x@Wq) @ [ gelu( (Wk^T (x^T x) Wv) * SCALE ) @ Wp_h ] + b
// via G_b = x_b^T x_b (symmetric) ; T_b = G_b @ Wv ; kv_h = Wk_h^T T_h

typedef __attribute__((ext_vector_type(8))) short short8_t;
typedef __attribute__((ext_vector_type(4))) float f32x4_t;

typedef __attribute__((address_space(1))) void as1_void;
typedef __attribute__((address_space(3))) void as3_void;

__device__ __forceinline__ void gload_lds16(const void* g, void* l) {
    __builtin_amdgcn_global_load_lds(
        (as1_void*)(unsigned long long)(g),
        (as3_void*)(unsigned long long)(l), 16, 0, 0);
}

// fast gelu (tanh form, branchless); |err| < ~1e-3 vs erf-gelu, below bf16 rounding.
__device__ __forceinline__ float gelu_f(float x) {
    float x2 = x * x;
    float t = x * fmaf(0.0356774081f, x2, 0.7978845608f);
    float e = __expf(2.0f * t);
    float th = 1.0f - 2.0f / (e + 1.0f);
    return 0.5f * x * (1.0f + th);
}

__device__ __forceinline__ unsigned short to_bf16(float f) {
    __hip_bfloat16 h = __float2bfloat16(f);
    return *reinterpret_cast<unsigned short*>(&h);
}

__device__ __forceinline__ f32x4_t mfma16(short8_t a, short8_t b, f32x4_t c) {
    return __builtin_amdgcn_mfma_f32_16x16x32_bf16(a, b, c, 0, 0, 0);
}

// ---------------- merged prep: x cvt / wqkvT / wprojT / wqkv_bf ----------------
// blocks [0,2048): x cvt; [2048,2912): wqkvT; [2912,3200): wprojT; [3200,3632): wqkv cvt.
__global__ __launch_bounds__(256) void k_prep(const float* __restrict__ x,
                                              const float* __restrict__ w_qkv,
                                              const float* __restrict__ w_proj,
                                              unsigned short* __restrict__ xb,
                                              unsigned short* __restrict__ wqkvT,
                                              unsigned short* __restrict__ wpT,
                                              unsigned short* __restrict__ wqkv_bf) {
    const int blk = blockIdx.x, tid = threadIdx.x;
    if (blk < 2048) {
        long i = (long)blk * 256 + tid;
        long stride = 2048L * 256;
        for (long idx = i * 4; idx < 50331648L; idx += stride * 4) {
            float4 v = *(const float4*)(x + idx);
            ushort4 o;
            o.x = to_bf16(v.x); o.y = to_bf16(v.y); o.z = to_bf16(v.z); o.w = to_bf16(v.w);
            *(ushort4*)(xb + idx) = o;
        }
    } else if (blk < 2912) {
        int gid = (blk - 2048) * 256 + tid;        // 2304*96
        int c = gid / 96, r0 = (gid % 96) * 8;
        short8_t o;
#pragma unroll
        for (int i = 0; i < 8; ++i)
            o[i] = (short)to_bf16(w_qkv[(size_t)(r0 + i) * 2304 + c]);
        *(short8_t*)(wqkvT + (size_t)c * 768 + r0) = o;
    } else if (blk < 3200) {
        int gid = (blk - 2912) * 256 + tid;        // 768*96
        int c = gid / 96, r0 = (gid % 96) * 8;
        short8_t o;
#pragma unroll
        for (int i = 0; i < 8; ++i)
            o[i] = (short)to_bf16(w_proj[(size_t)(r0 + i) * 768 + c]);
        *(short8_t*)(wpT + (size_t)c * 768 + r0) = o;
    } else {
        long i = (long)(blk - 3200) * 256 + tid;
        long stride = 432L * 256;
        for (long idx = i * 4; idx < 1769472L; idx += stride * 4) {
            float4 v = *(const float4*)(w_qkv + idx);
            ushort4 o;
            o.x = to_bf16(v.x); o.y = to_bf16(v.y); o.z = to_bf16(v.z); o.w = to_bf16(v.w);
            *(ushort4*)(wqkv_bf + idx) = o;
        }
    }
}

// ================= 256x256 GEMM: reads-one-phase-ahead + counted gates =================
template<bool GELU_EPI, bool BATCHED_B, bool BF16_OUT, bool BIAS>
__global__ __launch_bounds__(512, 2)
void k_gemm256(const unsigned short* __restrict__ A, int lda,
               const unsigned short* __restrict__ Bt, int ldb,
               void* __restrict__ Cout, int ldc,
               const float* __restrict__ bias,
               int tiles_n, int K) {
    __shared__ __attribute__((aligned(16))) unsigned short lds[2][2][2][128 * 64];

    const int nwg = gridDim.x;
    int bid = blockIdx.x;
    bid = (bid & 7) * (nwg >> 3) + (bid >> 3);

    const int tn = bid % tiles_n, tm = bid / tiles_n;
    const int row0 = tm * 256, col0 = tn * 256;

    const unsigned short* Bb = Bt;
    if (BATCHED_B) Bb += (size_t)(row0 >> 12) * 768 * 768;

    const int tid = threadIdx.x;
    const int lane = tid & 63;
    const int w = tid >> 6;
    const int wm = w >> 2;
    const int wn = w & 3;
    const int lr = lane & 15, lg = lane >> 4;

    const int c0 = tid, c1 = 512 + tid;
    const int sr0 = c0 >> 3, sk0 = (c0 & 7) ^ (sr0 & 7);
    const int sr1 = c1 >> 3, sk1 = (c1 & 7) ^ (sr1 & 7);

    auto stageA = [&](int buf, int half, int kt) {
        const unsigned short* base = A + (size_t)(row0 + half * 128) * lda + kt * 64;
        gload_lds16(base + (size_t)sr0 * lda + sk0 * 8, &lds[0][buf][half][c0 * 8]);
        gload_lds16(base + (size_t)sr1 * lda + sk1 * 8, &lds[0][buf][half][c1 * 8]);
    };
    auto stageB = [&](int buf, int half, int kt) {
        const unsigned short* base = Bb + (size_t)(col0 + half * 128) * ldb + kt * 64;
        gload_lds16(base + (size_t)sr0 * ldb + sk0 * 8, &lds[1][buf][half][c0 * 8]);
        gload_lds16(base + (size_t)sr1 * ldb + sk1 * 8, &lds[1][buf][half][c1 * 8]);
    };
    auto ldA = [&](int buf, int mi, int ks) -> short8_t {
        int row = mi * 16 + lr;
        int kc = (ks * 4 + lg) ^ (row & 7);
        return *(const short8_t*)&lds[0][buf][wm][row * 64 + kc * 8];
    };
    auto ldB = [&](int buf, int nj, int ks) -> short8_t {
        int row = wn * 64 + nj * 16 + lr;
        int half = row >> 7, rl = row & 127;
        int kc = (ks * 4 + lg) ^ (rl & 7);
        return *(const short8_t*)&lds[1][buf][half][rl * 64 + kc * 8];
    };

    f32x4_t acc[8][4] = {};
    short8_t bfrag[4][2];
    short8_t afrP[2][4];

#define FENCE asm volatile("" ::: "memory")
#define MFMACL(r0i, par)                                                        \
    __builtin_amdgcn_s_setprio(1);                                              \
    _Pragma("unroll") for (int nj = 0; nj < 4; ++nj) {                          \
        acc[r0i][nj]     = mfma16(afrP[par][0], bfrag[nj][0], acc[r0i][nj]);    \
        acc[r0i][nj]     = mfma16(afrP[par][1], bfrag[nj][1], acc[r0i][nj]);    \
        acc[r0i + 1][nj] = mfma16(afrP[par][2], bfrag[nj][0], acc[r0i + 1][nj]);\
        acc[r0i + 1][nj] = mfma16(afrP[par][3], bfrag[nj][1], acc[r0i + 1][nj]);\
    }                                                                           \
    __builtin_amdgcn_s_setprio(0);

#define GROUP(cb, nb, tnx)                                                      \
    { afrP[0][0] = ldA(cb, 0, 0); afrP[0][1] = ldA(cb, 0, 1);                   \
      afrP[0][2] = ldA(cb, 1, 0); afrP[0][3] = ldA(cb, 1, 1);                   \
      afrP[1][0] = ldA(cb, 2, 0); afrP[1][1] = ldA(cb, 2, 1);                   \
      afrP[1][2] = ldA(cb, 3, 0); afrP[1][3] = ldA(cb, 3, 1);                   \
      asm volatile("s_waitcnt lgkmcnt(4)" ::: "memory");                        \
      __builtin_amdgcn_sched_barrier(0);                                        \
      MFMACL(0, 0)                                                              \
      stageB(cb, 0, tnx);                                                       \
      FENCE; __builtin_amdgcn_s_barrier(); FENCE;                               \
      afrP[0][0] = ldA(cb, 4, 0); afrP[0][1] = ldA(cb, 4, 1);                   \
      afrP[0][2] = ldA(cb, 5, 0); afrP[0][3] = ldA(cb, 5, 1);                   \
      asm volatile("s_waitcnt lgkmcnt(4)" ::: "memory");                        \
      __builtin_amdgcn_sched_barrier(0);                                        \
      MFMACL(2, 1)                                                              \
      stageB(cb, 1, tnx);                                                       \
      FENCE; __builtin_amdgcn_s_barrier(); FENCE;                               \
      afrP[1][0] = ldA(cb, 6, 0); afrP[1][1] = ldA(cb, 6, 1);                   \
      afrP[1][2] = ldA(cb, 7, 0); afrP[1][3] = ldA(cb, 7, 1);                   \
      asm volatile("s_waitcnt lgkmcnt(4)" ::: "memory");                        \
      __builtin_amdgcn_sched_barrier(0);                                        \
      MFMACL(4, 0)                                                              \
      asm volatile("s_waitcnt vmcnt(8)" ::: "memory");                          \
      FENCE; __builtin_amdgcn_s_barrier(); FENCE;                               \
      asm volatile("s_waitcnt lgkmcnt(0)" ::: "memory");                        \
      __builtin_amdgcn_sched_barrier(0);                                        \
      MFMACL(6, 1)                                                              \
      _Pragma("unroll") for (int nj = 0; nj < 4; ++nj)                          \
          _Pragma("unroll") for (int ks = 0; ks < 2; ++ks)                      \
              bfrag[nj][ks] = ldB(nb, nj, ks);                                  \
      stageA(cb, 0, tnx); stageA(cb, 1, tnx);                                   \
      asm volatile("s_waitcnt vmcnt(8)" ::: "memory");                          \
      FENCE; __builtin_amdgcn_s_barrier(); FENCE;                               \
    }

    const int nt = K >> 6;
    const int niter = nt >> 1;

    stageA(0, 0, 0); stageA(0, 1, 0); stageB(0, 0, 0); stageB(0, 1, 0);
    asm volatile("s_waitcnt vmcnt(0)" ::: "memory");
    __builtin_amdgcn_s_barrier();
    FENCE;
    stageB(1, 0, 1); stageB(1, 1, 1); stageA(1, 0, 1); stageA(1, 1, 1);
#pragma unroll
    for (int nj = 0; nj < 4; ++nj)
#pragma unroll
        for (int ks = 0; ks < 2; ++ks)
            bfrag[nj][ks] = ldB(0, nj, ks);
    asm volatile("s_waitcnt lgkmcnt(0)" ::: "memory");
    FENCE;

    for (int it = 0; it < niter; ++it) {
        const int tA = (2 * it + 2 < nt) ? 2 * it + 2 : 0;
        const int tB = (2 * it + 3 < nt) ? 2 * it + 3 : 0;
        GROUP(0, 1, tA);
        GROUP(1, 0, tB);
    }
    asm volatile("s_waitcnt vmcnt(0)" ::: "memory");
#undef GROUP
#undef MFMACL
#undef FENCE

    const int rbase = row0 + wm * 128 + (lg << 2);
    const int cbase = col0 + wn * 64 + lr;
#pragma unroll
    for (int mi = 0; mi < 8; ++mi)
#pragma unroll
        for (int nj = 0; nj < 4; ++nj)
#pragma unroll
            for (int r = 0; r < 4; ++r) {
                int row = rbase + mi * 16 + r;
                int col = cbase + nj * 16;
                float v = acc[mi][nj][r];
                if (GELU_EPI) v = gelu_f(v);
                if (BIAS) v += bias[col];
                if (BF16_OUT)
                    ((unsigned short*)Cout)[(size_t)row * ldc + col] = to_bf16(v);
                else
                    ((float*)Cout)[(size_t)row * ldc + col] = v;
            }
}

// ================= 128x128 GEMM (bf16 out): 4 waves, 32KB LDS (small L2-resident GEMMs) =================
__global__ __launch_bounds__(256)
void k_gemm128(const unsigned short* __restrict__ A, int lda,
               const unsigned short* __restrict__ Bt, int ldb,
               unsigned short* __restrict__ C, int ldc,
               int tiles_n, int K) {
    __shared__ __attribute__((aligned(16))) unsigned short As[128 * 64];
    __shared__ __attribute__((aligned(16))) unsigned short Bs[128 * 64];

    const int nwg = gridDim.x;
    int bid = blockIdx.x;
    bid = (bid & 7) * (nwg >> 3) + (bid >> 3);   // nwg % 8 == 0

    const int tn = bid % tiles_n, tm = bid / tiles_n;
    const int row0 = tm * 128, col0 = tn * 128;

    const int tid = threadIdx.x, lane = tid & 63, w = tid >> 6;
    const int wm = w >> 1, wn = w & 1;
    const int lr = lane & 15, lg = lane >> 4;

    f32x4_t acc[4][4] = {};

    const int nt = K >> 6;
    for (int kt = 0; kt < nt; ++kt) {
#pragma unroll
        for (int i = 0; i < 4; ++i) {
            int ch = i * 256 + tid;
            int sr = ch >> 3, sk = (ch & 7) ^ (sr & 7);
            gload_lds16(A + (size_t)(row0 + sr) * lda + kt * 64 + sk * 8, As + ch * 8);
            gload_lds16(Bt + (size_t)(col0 + sr) * ldb + kt * 64 + sk * 8, Bs + ch * 8);
        }
        __syncthreads();
#pragma unroll
        for (int ks = 0; ks < 2; ++ks) {
            short8_t a[4], b[4];
#pragma unroll
            for (int mi = 0; mi < 4; ++mi) {
                int row = wm * 64 + mi * 16 + lr;
                a[mi] = *(const short8_t*)(As + row * 64 + (((ks * 4 + lg) ^ (row & 7)) << 3));
            }
#pragma unroll
            for (int nj = 0; nj < 4; ++nj) {
                int row = wn * 64 + nj * 16 + lr;
                b[nj] = *(const short8_t*)(Bs + row * 64 + (((ks * 4 + lg) ^ (row & 7)) << 3));
            }
#pragma unroll
            for (int mi = 0; mi < 4; ++mi)
#pragma unroll
                for (int nj = 0; nj < 4; ++nj)
                    acc[mi][nj] = mfma16(a[mi], b[nj], acc[mi][nj]);
        }
        __syncthreads();
    }

    const int rbase = row0 + wm * 64 + (lg << 2);
    const int cbase = col0 + wn * 64 + lr;
#pragma unroll
    for (int mi = 0; mi < 4; ++mi)
#pragma unroll
        for (int nj = 0; nj < 4; ++nj)
#pragma unroll
            for (int r = 0; r < 4; ++r)
                C[(size_t)(rbase + mi * 16 + r) * ldc + cbase + nj * 16] = to_bf16(acc[mi][nj][r]);
}

// ---------------- G_b = x_b^T x_b : symmetric, 21 upper 128x128 tiles ----------------
__global__ __launch_bounds__(256) void k_G(const unsigned short* __restrict__ xb,
                                           unsigned short* __restrict__ Gst) {
    static const signed char TI[21] = {0,0,0,0,0,0,1,1,1,1,1,2,2,2,2,3,3,3,4,4,5};
    static const signed char TJ[21] = {0,1,2,3,4,5,1,2,3,4,5,2,3,4,5,3,4,5,4,5,5};
    int bid = blockIdx.x;
    bid = (bid & 7) * 42 + (bid >> 3);            // 336 = 8*42, bijective
    const int b = bid / 21, t = bid % 21;
    const int d0 = TI[t] * 128, e0 = TJ[t] * 128;
    const bool diag = (d0 == e0);
    const unsigned short* xB = xb + (size_t)b * 4096 * 768;

    __shared__ __attribute__((aligned(16))) unsigned short lds[2][2][128 * 64];

    const int tid = threadIdx.x, lane = tid & 63, w = tid >> 6;
    const int colg = tid & 15;
    const int rq8 = (tid >> 4) & 7;
    const int blk = tid >> 7;
    const int wm = w >> 1, wn = w & 1;
    const int lr = lane & 15, lg = lane >> 4;
    const int base0 = (blk ? e0 : d0) + colg * 8;
    const int tb = diag ? 0 : 1;
    const bool active = (!diag) || (blk == 0);

    f32x4_t acc[4][4] = {};
    short8_t ra[8];

    auto loadx = [&](int it) {
        if (!active) return;
        const size_t rbase = (size_t)(it * 64 + rq8 * 8) * 768 + base0;
#pragma unroll
        for (int rr = 0; rr < 8; ++rr)
            ra[rr] = *(const short8_t*)(xB + rbase + (size_t)rr * 768);
    };
    auto writes = [&](int buf) {
        if (!active) return;
#pragma unroll
        for (int j = 0; j < 8; ++j) {
            const int c = colg * 8 + j;
            const int sw3 = ((c & 7) ^ (c >> 3)) & 7;
            short8_t v;
#pragma unroll
            for (int rr = 0; rr < 8; ++rr) v[rr] = ra[rr][j];
            *(short8_t*)(&lds[buf][blk][c * 64 + ((rq8 ^ sw3) << 3)]) = v;
        }
    };
    auto ldfrag = [&](int buf, int tile, int cbase, int o) -> short8_t {
        const int c = cbase + lr;
        const int sw3 = ((c & 7) ^ (c >> 3)) & 7;
        return *(const short8_t*)(&lds[buf][tile][c * 64 + ((o ^ sw3) << 3)]);
    };

    loadx(0);
    writes(0);
    __syncthreads();

    for (int it = 0; it < 64; ++it) {
        const int buf = it & 1;
        if (it < 63) loadx(it + 1);
#pragma unroll
        for (int ks = 0; ks < 2; ++ks) {
            short8_t af[4], bf[4];
#pragma unroll
            for (int mi = 0; mi < 4; ++mi)
                af[mi] = ldfrag(buf, 0, wm * 64 + mi * 16, ks * 4 + lg);
#pragma unroll
            for (int nj = 0; nj < 4; ++nj)
                bf[nj] = ldfrag(buf, tb, wn * 64 + nj * 16, ks * 4 + lg);
#pragma unroll
            for (int mi = 0; mi < 4; ++mi)
#pragma unroll
                for (int nj = 0; nj < 4; ++nj)
                    acc[mi][nj] = mfma16(af[mi], bf[nj], acc[mi][nj]);
        }
        if (it < 63) writes(buf ^ 1);
        __syncthreads();
    }

    const int dbase = d0 + wm * 64 + (lg << 2);
    const int ebase = e0 + wn * 64 + lr;
#pragma unroll
    for (int mi = 0; mi < 4; ++mi)
#pragma unroll
        for (int nj = 0; nj < 4; ++nj)
#pragma unroll
            for (int r = 0; r < 4; ++r)
                Gst[((size_t)b * 768 + dbase + mi * 16 + r) * 768 + ebase + nj * 16] =
                    to_bf16(acc[mi][nj][r]);

    if (!diag) {
        unsigned short* T = &lds[0][0][0];
#pragma unroll
        for (int mi = 0; mi < 4; ++mi)
#pragma unroll
            for (int nj = 0; nj < 4; ++nj) {
                const int el = wn * 64 + nj * 16 + lr;
                const int sig = ((el ^ (el >> 3)) & 7) << 1;
                const int s = wm * 16 + mi * 4 + lg;
                uint2 pk;
                pk.x = (unsigned int)to_bf16(acc[mi][nj][0]) |
                       ((unsigned int)to_bf16(acc[mi][nj][1]) << 16);
                pk.y = (unsigned int)to_bf16(acc[mi][nj][2]) |
                       ((unsigned int)to_bf16(acc[mi][nj][3]) << 16);
                *(uint2*)(&T[el * 128 + ((s ^ sig) << 2)]) = pk;
            }
        __syncthreads();
#pragma unroll
        for (int i = 0; i < 8; ++i) {
            const int el = i * 16 + (tid >> 4);
            const int p = tid & 15;
            const int sig = ((el ^ (el >> 3)) & 7) << 1;
            short8_t v = *(const short8_t*)(&T[el * 128 + (((2 * p) ^ sig) << 2)]);
            *(short8_t*)(Gst + ((size_t)b * 768 + e0 + el) * 768 + d0 + p * 8) = v;
        }
    }
}

// ---------------- merged: kv_h = Wk_h^T T_h (scale+gelu) then M-tiles -> MT ----------------
__global__ __launch_bounds__(256) void k_kvM(const unsigned short* __restrict__ wqkv_bf,
                                             const unsigned short* __restrict__ Tst,
                                             const unsigned short* __restrict__ wpT,
                                             unsigned short* __restrict__ MT) {
    const int bh = blockIdx.x;
    const int b = bh / 12, h = bh % 12;
    const unsigned short* kptr = wqkv_bf + 768 + h * 64;
    const unsigned short* vptr = Tst + (size_t)b * 768 * 768 + h * 64;

    __shared__ __attribute__((aligned(16))) unsigned short kT[64 * 64];
    __shared__ __attribute__((aligned(16))) unsigned short vT[64 * 64];
    __shared__ __attribute__((aligned(16))) unsigned short As[64 * 64];
    __shared__ __attribute__((aligned(16))) unsigned short Bs[256 * 64];

    const int tid = threadIdx.x, lane = tid & 63, w = tid >> 6;
    const int np = tid >> 3;
    const int g = tid & 7;
    const int lr = lane & 15, lg = lane >> 4;

    f32x4_t acc[4] = {};

    for (int it = 0; it < 12; ++it) {
        const size_t r = (size_t)(it * 64 + 2 * np);
        short8_t k0 = *(const short8_t*)(kptr + r * 2304 + g * 8);
        short8_t k1 = *(const short8_t*)(kptr + (r + 1) * 2304 + g * 8);
        short8_t v0 = *(const short8_t*)(vptr + r * 768 + g * 8);
        short8_t v1 = *(const short8_t*)(vptr + (r + 1) * 768 + g * 8);
        __syncthreads();
#pragma unroll
        for (int j = 0; j < 8; ++j) {
            const int d = g * 8 + j;
            const int e = d * 64 + ((2 * np) ^ (((d ^ (d >> 3)) & 7) << 3));
            *(unsigned int*)(kT + e) =
                (unsigned int)(unsigned short)k0[j] | ((unsigned int)(unsigned short)k1[j] << 16);
            *(unsigned int*)(vT + e) =
                (unsigned int)(unsigned short)v0[j] | ((unsigned int)(unsigned short)v1[j] << 16);
        }
        __syncthreads();
#pragma unroll
        for (int ks = 0; ks < 2; ++ks) {
            const int d = w * 16 + lr;
            short8_t a = *(const short8_t*)(kT + d * 64 +
                (((ks * 4 + lg) ^ ((d ^ (d >> 3)) & 7)) << 3));
#pragma unroll
            for (int nj = 0; nj < 4; ++nj) {
                const int e2 = nj * 16 + lr;
                short8_t bf = *(const short8_t*)(vT + e2 * 64 +
                    (((ks * 4 + lg) ^ ((e2 ^ (e2 >> 3)) & 7)) << 3));
                acc[nj] = __builtin_amdgcn_mfma_f32_16x16x32_bf16(a, bf, acc[nj], 0, 0, 0);
            }
        }
    }

    // gelu'd kv -> As [d:64][e:64] bf16, 8-chunk swizzled: chunk' = (e>>3) ^ (d&7)
    {
        const int drow = w * 16 + (lg << 2);
#pragma unroll
        for (int nj = 0; nj < 4; ++nj)
#pragma unroll
            for (int r = 0; r < 4; ++r) {
                const int d = drow + r;
                const int e = nj * 16 + lr;
                As[d * 64 + ((((e >> 3) ^ (d & 7)) << 3) | (e & 7))] =
                    to_bf16(gelu_f(acc[nj][r] * 0.125f));
            }
    }

    for (int ct = 0; ct < 3; ++ct) {
        const int c0 = ct * 256;
        short8_t rb[8];
#pragma unroll
        for (int i = 0; i < 8; ++i) {
            int ch = i * 256 + tid, row = ch >> 3, kc = ch & 7;
            rb[i] = *(const short8_t*)(wpT + (size_t)(c0 + row) * 768 + h * 64 + kc * 8);
        }
        __syncthreads();
#pragma unroll
        for (int i = 0; i < 8; ++i) {
            int ch = i * 256 + tid, row = ch >> 3, kc = ch & 7;
            *(short8_t*)(Bs + row * 64 + ((kc ^ (row & 7)) * 8)) = rb[i];
        }
        __syncthreads();

        f32x4_t acc2[4][4] = {};
#pragma unroll
        for (int ks = 0; ks < 2; ++ks) {
            short8_t a[4], bfr[4];
#pragma unroll
            for (int mi = 0; mi < 4; ++mi) {
                int row = mi * 16 + lr;
                a[mi] = *(const short8_t*)(As + row * 64 + (((ks * 4 + lg) ^ (row & 7)) * 8));
            }
#pragma unroll
            for (int nj = 0; nj < 4; ++nj) {
                int row = w * 64 + nj * 16 + lr;
                bfr[nj] = *(const short8_t*)(Bs + row * 64 + (((ks * 4 + lg) ^ (row & 7)) * 8));
            }
#pragma unroll
            for (int mi = 0; mi < 4; ++mi)
#pragma unroll
                for (int nj = 0; nj < 4; ++nj)
                    acc2[mi][nj] = __builtin_amdgcn_mfma_f32_16x16x32_bf16(a[mi], bfr[nj], acc2[mi][nj], 0, 0, 0);
        }
        __syncthreads();

#pragma unroll
        for (int mi = 0; mi < 4; ++mi)
#pragma unroll
            for (int nj = 0; nj < 4; ++nj) {
                unsigned int w0 = (unsigned int)to_bf16(acc2[mi][nj][0]) |
                                  ((unsigned int)to_bf16(acc2[mi][nj][1]) << 16);
                unsigned int w1 = (unsigned int)to_bf16(acc2[mi][nj][2]) |
                                  ((unsigned int)to_bf16(acc2[mi][nj][3]) << 16);
                uint2 pk; pk.x = w0; pk.y = w1;
                *(uint2*)(Bs + (w * 64 + nj * 16 + lr) * 64 + mi * 16 + lg * 4) = pk;
            }
        __syncthreads();
#pragma unroll
        for (int i = 0; i < 8; ++i) {
            int ch = i * 256 + tid, cl = ch >> 3, dk = ch & 7;
            short8_t v = *(const short8_t*)(Bs + cl * 64 + dk * 8);
            *(short8_t*)(MT + ((size_t)(b * 768) + c0 + cl) * 768 + h * 64 + dk * 8) = v;
        }
    }
}

extern "C" void kernel_launch(void* const* d_in, const int* in_sizes, int n_in,
                              void* d_out, int out_size, void* d_ws, size_t ws_size,
                              hipStream_t stream) {
    const float* x      = (const float*)d_in[0];
    const float* w_qkv  = (const float*)d_in[1];
    const float* w_proj = (const float*)d_in[2];
    const float* b_proj = (const float*)d_in[3];
    float* out = (float*)d_out;
    char* ws = (char*)d_ws;

    unsigned short* q_gelu  = (unsigned short*)(ws);               // 100,663,296
    unsigned short* wqkvT   = (unsigned short*)(ws + 100663296);   //   3,538,944
    unsigned short* wqkv_bf = (unsigned short*)(ws + 104202240);   //   3,538,944
    unsigned short* G_bf    = (unsigned short*)(ws + 107741184);   //  18,874,368
    unsigned short* T_bf    = (unsigned short*)(ws + 126615552);   //  18,874,368
    unsigned short* MT      = (unsigned short*)(ws + 145489920);   //  18,874,368
    unsigned short* xb   = (unsigned short*)d_out;                 // scratch in d_out
    unsigned short* wpT  = (unsigned short*)((char*)d_out + 136314880);

    // 1) merged prep: x->bf16, weight transposes, wqkv cvt
    k_prep<<<3632, 256, 0, stream>>>(x, w_qkv, w_proj, xb, wqkvT, wpT, wqkv_bf);
    // 2) GEMM1q: q_gelu = gelu(xb @ Wq^T)  [65536,768]
    k_gemm256<true, false, true, false><<<768, 512, 0, stream>>>(
        xb, 768, wqkvT, 768, q_gelu, 768, nullptr, 3, 768);
    // 3) G_b = x_b^T x_b (symmetric, 21 upper tiles per batch)
    k_G<<<336, 256, 0, stream>>>(xb, G_bf);
    // 4) T_b = G_b @ Wv
    k_gemm128<<<576, 256, 0, stream>>>(
        G_bf, 768, wqkvT + (size_t)1536 * 768, 768, T_bf, 768, 6, 768);
    // 5) kv_h + M fold
    k_kvM<<<192, 256, 0, stream>>>(wqkv_bf, T_bf, wpT, MT);
    // 6) GEMM2: out = q_gelu @ MT_b^T + b_proj
    k_gemm256<false, true, false, true><<<768, 512, 0, stream>>>(
        q_gelu, 768, MT, 768, out, 768, b_proj, 3, 768);
}

// Round 16
// 385.725 us; speedup vs baseline: 1.1438x; 1.0087x over previous
//
#include <hip/hip_runtime.h>
#include <hip/hip_bf16.h>

// Problem: B=16, N=4096, C=768, H=12, D=64
// out = gelu(x@Wq) @ [ gelu( (Wk^T (x^T x) Wv) * SCALE ) @ Wp_h ] + b
// via G_b = x_b^T x_b (symmetric) ; T_b = G_b @ Wv ; kv_h = Wk_h^T T_h

typedef __attribute__((ext_vector_type(8))) short short8_t;
typedef __attribute__((ext_vector_type(4))) float f32x4_t;

typedef __attribute__((address_space(1))) void as1_void;
typedef __attribute__((address_space(3))) void as3_void;

__device__ __forceinline__ void gload_lds16(const void* g, void* l) {
    __builtin_amdgcn_global_load_lds(
        (as1_void*)(unsigned long long)(g),
        (as3_void*)(unsigned long long)(l), 16, 0, 0);
}

// fast gelu (tanh form, branchless); |err| < ~1e-3 vs erf-gelu, below bf16 rounding.
__device__ __forceinline__ float gelu_f(float x) {
    float x2 = x * x;
    float t = x * fmaf(0.0356774081f, x2, 0.7978845608f);
    float e = __expf(2.0f * t);
    float th = 1.0f - 2.0f / (e + 1.0f);
    return 0.5f * x * (1.0f + th);
}

__device__ __forceinline__ unsigned short to_bf16(float f) {
    __hip_bfloat16 h = __float2bfloat16(f);
    return *reinterpret_cast<unsigned short*>(&h);
}

__device__ __forceinline__ f32x4_t mfma16(short8_t a, short8_t b, f32x4_t c) {
    return __builtin_amdgcn_mfma_f32_16x16x32_bf16(a, b, c, 0, 0, 0);
}

// ---------------- merged prep: x cvt / wqkvT / wprojT / wqkv_bf ----------------
// blocks [0,2048): x cvt; [2048,2912): wqkvT; [2912,3200): wprojT; [3200,3632): wqkv cvt.
__global__ __launch_bounds__(256) void k_prep(const float* __restrict__ x,
                                              const float* __restrict__ w_qkv,
                                              const float* __restrict__ w_proj,
                                              unsigned short* __restrict__ xb,
                                              unsigned short* __restrict__ wqkvT,
                                              unsigned short* __restrict__ wpT,
                                              unsigned short* __restrict__ wqkv_bf) {
    const int blk = blockIdx.x, tid = threadIdx.x;
    if (blk < 2048) {
        long i = (long)blk * 256 + tid;
        long stride = 2048L * 256;
        for (long idx = i * 4; idx < 50331648L; idx += stride * 4) {
            float4 v = *(const float4*)(x + idx);
            ushort4 o;
            o.x = to_bf16(v.x); o.y = to_bf16(v.y); o.z = to_bf16(v.z); o.w = to_bf16(v.w);
            *(ushort4*)(xb + idx) = o;
        }
    } else if (blk < 2912) {
        int gid = (blk - 2048) * 256 + tid;        // 2304*96
        int c = gid / 96, r0 = (gid % 96) * 8;
        short8_t o;
#pragma unroll
        for (int i = 0; i < 8; ++i)
            o[i] = (short)to_bf16(w_qkv[(size_t)(r0 + i) * 2304 + c]);
        *(short8_t*)(wqkvT + (size_t)c * 768 + r0) = o;
    } else if (blk < 3200) {
        int gid = (blk - 2912) * 256 + tid;        // 768*96
        int c = gid / 96, r0 = (gid % 96) * 8;
        short8_t o;
#pragma unroll
        for (int i = 0; i < 8; ++i)
            o[i] = (short)to_bf16(w_proj[(size_t)(r0 + i) * 768 + c]);
        *(short8_t*)(wpT + (size_t)c * 768 + r0) = o;
    } else {
        long i = (long)(blk - 3200) * 256 + tid;
        long stride = 432L * 256;
        for (long idx = i * 4; idx < 1769472L; idx += stride * 4) {
            float4 v = *(const float4*)(w_qkv + idx);
            ushort4 o;
            o.x = to_bf16(v.x); o.y = to_bf16(v.y); o.z = to_bf16(v.z); o.w = to_bf16(v.w);
            *(ushort4*)(wqkv_bf + idx) = o;
        }
    }
}

// ================= 256x256 GEMM: reads-one-phase-ahead + counted gates =================
template<bool GELU_EPI, bool BATCHED_B, bool BF16_OUT, bool BIAS>
__global__ __launch_bounds__(512, 2)
void k_gemm256(const unsigned short* __restrict__ A, int lda,
               const unsigned short* __restrict__ Bt, int ldb,
               void* __restrict__ Cout, int ldc,
               const float* __restrict__ bias,
               int tiles_n, int K) {
    __shared__ __attribute__((aligned(16))) unsigned short lds[2][2][2][128 * 64];

    const int nwg = gridDim.x;
    int bid = blockIdx.x;
    bid = (bid & 7) * (nwg >> 3) + (bid >> 3);

    const int tn = bid % tiles_n, tm = bid / tiles_n;
    const int row0 = tm * 256, col0 = tn * 256;

    const unsigned short* Bb = Bt;
    if (BATCHED_B) Bb += (size_t)(row0 >> 12) * 768 * 768;

    const int tid = threadIdx.x;
    const int lane = tid & 63;
    const int w = tid >> 6;
    const int wm = w >> 2;
    const int wn = w & 3;
    const int lr = lane & 15, lg = lane >> 4;

    const int c0 = tid, c1 = 512 + tid;
    const int sr0 = c0 >> 3, sk0 = (c0 & 7) ^ (sr0 & 7);
    const int sr1 = c1 >> 3, sk1 = (c1 & 7) ^ (sr1 & 7);

    auto stageA = [&](int buf, int half, int kt) {
        const unsigned short* base = A + (size_t)(row0 + half * 128) * lda + kt * 64;
        gload_lds16(base + (size_t)sr0 * lda + sk0 * 8, &lds[0][buf][half][c0 * 8]);
        gload_lds16(base + (size_t)sr1 * lda + sk1 * 8, &lds[0][buf][half][c1 * 8]);
    };
    auto stageB = [&](int buf, int half, int kt) {
        const unsigned short* base = Bb + (size_t)(col0 + half * 128) * ldb + kt * 64;
        gload_lds16(base + (size_t)sr0 * ldb + sk0 * 8, &lds[1][buf][half][c0 * 8]);
        gload_lds16(base + (size_t)sr1 * ldb + sk1 * 8, &lds[1][buf][half][c1 * 8]);
    };
    auto ldA = [&](int buf, int mi, int ks) -> short8_t {
        int row = mi * 16 + lr;
        int kc = (ks * 4 + lg) ^ (row & 7);
        return *(const short8_t*)&lds[0][buf][wm][row * 64 + kc * 8];
    };
    auto ldB = [&](int buf, int nj, int ks) -> short8_t {
        int row = wn * 64 + nj * 16 + lr;
        int half = row >> 7, rl = row & 127;
        int kc = (ks * 4 + lg) ^ (rl & 7);
        return *(const short8_t*)&lds[1][buf][half][rl * 64 + kc * 8];
    };

    f32x4_t acc[8][4] = {};
    short8_t bfrag[4][2];
    short8_t afrP[2][4];

#define FENCE asm volatile("" ::: "memory")
#define MFMACL(r0i, par)                                                        \
    __builtin_amdgcn_s_setprio(1);                                              \
    _Pragma("unroll") for (int nj = 0; nj < 4; ++nj) {                          \
        acc[r0i][nj]     = mfma16(afrP[par][0], bfrag[nj][0], acc[r0i][nj]);    \
        acc[r0i][nj]     = mfma16(afrP[par][1], bfrag[nj][1], acc[r0i][nj]);    \
        acc[r0i + 1][nj] = mfma16(afrP[par][2], bfrag[nj][0], acc[r0i + 1][nj]);\
        acc[r0i + 1][nj] = mfma16(afrP[par][3], bfrag[nj][1], acc[r0i + 1][nj]);\
    }                                                                           \
    __builtin_amdgcn_s_setprio(0);

#define GROUP(cb, nb, tnx)                                                      \
    { afrP[0][0] = ldA(cb, 0, 0); afrP[0][1] = ldA(cb, 0, 1);                   \
      afrP[0][2] = ldA(cb, 1, 0); afrP[0][3] = ldA(cb, 1, 1);                   \
      afrP[1][0] = ldA(cb, 2, 0); afrP[1][1] = ldA(cb, 2, 1);                   \
      afrP[1][2] = ldA(cb, 3, 0); afrP[1][3] = ldA(cb, 3, 1);                   \
      asm volatile("s_waitcnt lgkmcnt(4)" ::: "memory");                        \
      __builtin_amdgcn_sched_barrier(0);                                        \
      MFMACL(0, 0)                                                              \
      stageB(cb, 0, tnx);                                                       \
      FENCE; __builtin_amdgcn_s_barrier(); FENCE;                               \
      afrP[0][0] = ldA(cb, 4, 0); afrP[0][1] = ldA(cb, 4, 1);                   \
      afrP[0][2] = ldA(cb, 5, 0); afrP[0][3] = ldA(cb, 5, 1);                   \
      asm volatile("s_waitcnt lgkmcnt(4)" ::: "memory");                        \
      __builtin_amdgcn_sched_barrier(0);                                        \
      MFMACL(2, 1)                                                              \
      stageB(cb, 1, tnx);                                                       \
      FENCE; __builtin_amdgcn_s_barrier(); FENCE;                               \
      afrP[1][0] = ldA(cb, 6, 0); afrP[1][1] = ldA(cb, 6, 1);                   \
      afrP[1][2] = ldA(cb, 7, 0); afrP[1][3] = ldA(cb, 7, 1);                   \
      asm volatile("s_waitcnt lgkmcnt(4)" ::: "memory");                        \
      __builtin_amdgcn_sched_barrier(0);                                        \
      MFMACL(4, 0)                                                              \
      asm volatile("s_waitcnt vmcnt(8)" ::: "memory");                          \
      FENCE; __builtin_amdgcn_s_barrier(); FENCE;                               \
      asm volatile("s_waitcnt lgkmcnt(0)" ::: "memory");                        \
      __builtin_amdgcn_sched_barrier(0);                                        \
      MFMACL(6, 1)                                                              \
      _Pragma("unroll") for (int nj = 0; nj < 4; ++nj)                          \
          _Pragma("unroll") for (int ks = 0; ks < 2; ++ks)                      \
              bfrag[nj][ks] = ldB(nb, nj, ks);                                  \
      stageA(cb, 0, tnx); stageA(cb, 1, tnx);                                   \
      asm volatile("s_waitcnt vmcnt(8)" ::: "memory");                          \
      FENCE; __builtin_amdgcn_s_barrier(); FENCE;                               \
    }

    const int nt = K >> 6;
    const int niter = nt >> 1;

    stageA(0, 0, 0); stageA(0, 1, 0); stageB(0, 0, 0); stageB(0, 1, 0);
    asm volatile("s_waitcnt vmcnt(0)" ::: "memory");
    __builtin_amdgcn_s_barrier();
    FENCE;
    stageB(1, 0, 1); stageB(1, 1, 1); stageA(1, 0, 1); stageA(1, 1, 1);
#pragma unroll
    for (int nj = 0; nj < 4; ++nj)
#pragma unroll
        for (int ks = 0; ks < 2; ++ks)
            bfrag[nj][ks] = ldB(0, nj, ks);
    asm volatile("s_waitcnt lgkmcnt(0)" ::: "memory");
    FENCE;

    for (int it = 0; it < niter; ++it) {
        const int tA = (2 * it + 2 < nt) ? 2 * it + 2 : 0;
        const int tB = (2 * it + 3 < nt) ? 2 * it + 3 : 0;
        GROUP(0, 1, tA);
        GROUP(1, 0, tB);
    }
    asm volatile("s_waitcnt vmcnt(0)" ::: "memory");
#undef GROUP
#undef MFMACL
#undef FENCE

    const int rbase = row0 + wm * 128 + (lg << 2);
    const int cbase = col0 + wn * 64 + lr;
#pragma unroll
    for (int mi = 0; mi < 8; ++mi)
#pragma unroll
        for (int nj = 0; nj < 4; ++nj)
#pragma unroll
            for (int r = 0; r < 4; ++r) {
                int row = rbase + mi * 16 + r;
                int col = cbase + nj * 16;
                float v = acc[mi][nj][r];
                if (GELU_EPI) v = gelu_f(v);
                if (BIAS) v += bias[col];
                if (BF16_OUT)
                    ((unsigned short*)Cout)[(size_t)row * ldc + col] = to_bf16(v);
                else
                    ((float*)Cout)[(size_t)row * ldc + col] = v;
            }
}

// ================= 128x128 GEMM (bf16 out): 4 waves, 32KB LDS (small L2-resident GEMMs) =================
__global__ __launch_bounds__(256)
void k_gemm128(const unsigned short* __restrict__ A, int lda,
               const unsigned short* __restrict__ Bt, int ldb,
               unsigned short* __restrict__ C, int ldc,
               int tiles_n, int K) {
    __shared__ __attribute__((aligned(16))) unsigned short As[128 * 64];
    __shared__ __attribute__((aligned(16))) unsigned short Bs[128 * 64];

    const int nwg = gridDim.x;
    int bid = blockIdx.x;
    bid = (bid & 7) * (nwg >> 3) + (bid >> 3);   // nwg % 8 == 0

    const int tn = bid % tiles_n, tm = bid / tiles_n;
    const int row0 = tm * 128, col0 = tn * 128;

    const int tid = threadIdx.x, lane = tid & 63, w = tid >> 6;
    const int wm = w >> 1, wn = w & 1;
    const int lr = lane & 15, lg = lane >> 4;

    f32x4_t acc[4][4] = {};

    const int nt = K >> 6;
    for (int kt = 0; kt < nt; ++kt) {
#pragma unroll
        for (int i = 0; i < 4; ++i) {
            int ch = i * 256 + tid;
            int sr = ch >> 3, sk = (ch & 7) ^ (sr & 7);
            gload_lds16(A + (size_t)(row0 + sr) * lda + kt * 64 + sk * 8, As + ch * 8);
            gload_lds16(Bt + (size_t)(col0 + sr) * ldb + kt * 64 + sk * 8, Bs + ch * 8);
        }
        __syncthreads();
#pragma unroll
        for (int ks = 0; ks < 2; ++ks) {
            short8_t a[4], b[4];
#pragma unroll
            for (int mi = 0; mi < 4; ++mi) {
                int row = wm * 64 + mi * 16 + lr;
                a[mi] = *(const short8_t*)(As + row * 64 + (((ks * 4 + lg) ^ (row & 7)) << 3));
            }
#pragma unroll
            for (int nj = 0; nj < 4; ++nj) {
                int row = wn * 64 + nj * 16 + lr;
                b[nj] = *(const short8_t*)(Bs + row * 64 + (((ks * 4 + lg) ^ (row & 7)) << 3));
            }
#pragma unroll
            for (int mi = 0; mi < 4; ++mi)
#pragma unroll
                for (int nj = 0; nj < 4; ++nj)
                    acc[mi][nj] = mfma16(a[mi], b[nj], acc[mi][nj]);
        }
        __syncthreads();
    }

    const int rbase = row0 + wm * 64 + (lg << 2);
    const int cbase = col0 + wn * 64 + lr;
#pragma unroll
    for (int mi = 0; mi < 4; ++mi)
#pragma unroll
        for (int nj = 0; nj < 4; ++nj)
#pragma unroll
            for (int r = 0; r < 4; ++r)
                C[(size_t)(rbase + mi * 16 + r) * ldc + cbase + nj * 16] = to_bf16(acc[mi][nj][r]);
}

// ---------------- G_b = x_b^T x_b : symmetric, 21 upper 128x128 tiles ----------------
__global__ __launch_bounds__(256) void k_G(const unsigned short* __restrict__ xb,
                                           unsigned short* __restrict__ Gst) {
    static const signed char TI[21] = {0,0,0,0,0,0,1,1,1,1,1,2,2,2,2,3,3,3,4,4,5};
    static const signed char TJ[21] = {0,1,2,3,4,5,1,2,3,4,5,2,3,4,5,3,4,5,4,5,5};
    int bid = blockIdx.x;
    bid = (bid & 7) * 42 + (bid >> 3);            // 336 = 8*42, bijective
    const int b = bid / 21, t = bid % 21;
    const int d0 = TI[t] * 128, e0 = TJ[t] * 128;
    const bool diag = (d0 == e0);
    const unsigned short* xB = xb + (size_t)b * 4096 * 768;

    __shared__ __attribute__((aligned(16))) unsigned short lds[2][2][128 * 64];

    const int tid = threadIdx.x, lane = tid & 63, w = tid >> 6;
    const int colg = tid & 15;
    const int rq8 = (tid >> 4) & 7;
    const int blk = tid >> 7;
    const int wm = w >> 1, wn = w & 1;
    const int lr = lane & 15, lg = lane >> 4;
    const int base0 = (blk ? e0 : d0) + colg * 8;
    const int tb = diag ? 0 : 1;
    const bool active = (!diag) || (blk == 0);

    f32x4_t acc[4][4] = {};
    short8_t ra[8];

    auto loadx = [&](int it) {
        if (!active) return;
        const size_t rbase = (size_t)(it * 64 + rq8 * 8) * 768 + base0;
#pragma unroll
        for (int rr = 0; rr < 8; ++rr)
            ra[rr] = *(const short8_t*)(xB + rbase + (size_t)rr * 768);
    };
    auto writes = [&](int buf) {
        if (!active) return;
#pragma unroll
        for (int j = 0; j < 8; ++j) {
            const int c = colg * 8 + j;
            const int sw3 = ((c & 7) ^ (c >> 3)) & 7;
            short8_t v;
#pragma unroll
            for (int rr = 0; rr < 8; ++rr) v[rr] = ra[rr][j];
            *(short8_t*)(&lds[buf][blk][c * 64 + ((rq8 ^ sw3) << 3)]) = v;
        }
    };
    auto ldfrag = [&](int buf, int tile, int cbase, int o) -> short8_t {
        const int c = cbase + lr;
        const int sw3 = ((c & 7) ^ (c >> 3)) & 7;
        return *(const short8_t*)(&lds[buf][tile][c * 64 + ((o ^ sw3) << 3)]);
    };

    loadx(0);
    writes(0);
    __syncthreads();

    for (int it = 0; it < 64; ++it) {
        const int buf = it & 1;
        if (it < 63) loadx(it + 1);
#pragma unroll
        for (int ks = 0; ks < 2; ++ks) {
            short8_t af[4], bf[4];
#pragma unroll
            for (int mi = 0; mi < 4; ++mi)
                af[mi] = ldfrag(buf, 0, wm * 64 + mi * 16, ks * 4 + lg);
#pragma unroll
            for (int nj = 0; nj < 4; ++nj)
                bf[nj] = ldfrag(buf, tb, wn * 64 + nj * 16, ks * 4 + lg);
#pragma unroll
            for (int mi = 0; mi < 4; ++mi)
#pragma unroll
                for (int nj = 0; nj < 4; ++nj)
                    acc[mi][nj] = mfma16(af[mi], bf[nj], acc[mi][nj]);
        }
        if (it < 63) writes(buf ^ 1);
        __syncthreads();
    }

    const int dbase = d0 + wm * 64 + (lg << 2);
    const int ebase = e0 + wn * 64 + lr;
#pragma unroll
    for (int mi = 0; mi < 4; ++mi)
#pragma unroll
        for (int nj = 0; nj < 4; ++nj)
#pragma unroll
            for (int r = 0; r < 4; ++r)
                Gst[((size_t)b * 768 + dbase + mi * 16 + r) * 768 + ebase + nj * 16] =
                    to_bf16(acc[mi][nj][r]);

    if (!diag) {
        unsigned short* T = &lds[0][0][0];
#pragma unroll
        for (int mi = 0; mi < 4; ++mi)
#pragma unroll
            for (int nj = 0; nj < 4; ++nj) {
                const int el = wn * 64 + nj * 16 + lr;
                const int sig = ((el ^ (el >> 3)) & 7) << 1;
                const int s = wm * 16 + mi * 4 + lg;
                uint2 pk;
                pk.x = (unsigned int)to_bf16(acc[mi][nj][0]) |
                       ((unsigned int)to_bf16(acc[mi][nj][1]) << 16);
                pk.y = (unsigned int)to_bf16(acc[mi][nj][2]) |
                       ((unsigned int)to_bf16(acc[mi][nj][3]) << 16);
                *(uint2*)(&T[el * 128 + ((s ^ sig) << 2)]) = pk;
            }
        __syncthreads();
#pragma unroll
        for (int i = 0; i < 8; ++i) {
            const int el = i * 16 + (tid >> 4);
            const int p = tid & 15;
            const int sig = ((el ^ (el >> 3)) & 7) << 1;
            short8_t v = *(const short8_t*)(&T[el * 128 + (((2 * p) ^ sig) << 2)]);
            *(short8_t*)(Gst + ((size_t)b * 768 + e0 + el) * 768 + d0 + p * 8) = v;
        }
    }
}

// ---------------- merged: kv_h = Wk_h^T T_h (scale+gelu) then M-tiles -> MT ----------------
__global__ __launch_bounds__(256) void k_kvM(const unsigned short* __restrict__ wqkv_bf,
                                             const unsigned short* __restrict__ Tst,
                                             const unsigned short* __restrict__ wpT,
                                             unsigned short* __restrict__ MT) {
    const int bh = blockIdx.x;
    const int b = bh / 12, h = bh % 12;
    const unsigned short* kptr = wqkv_bf + 768 + h * 64;
    const unsigned short* vptr = Tst + (size_t)b * 768 * 768 + h * 64;

    __shared__ __attribute__((aligned(16))) unsigned short kT[64 * 64];
    __shared__ __attribute__((aligned(16))) unsigned short vT[64 * 64];
    __shared__ __attribute__((aligned(16))) unsigned short As[64 * 64];
    __shared__ __attribute__((aligned(16))) unsigned short Bs[256 * 64];

    const int tid = threadIdx.x, lane = tid & 63, w = tid >> 6;
    const int np = tid >> 3;
    const int g = tid & 7;
    const int lr = lane & 15, lg = lane >> 4;

    f32x4_t acc[4] = {};

    for (int it = 0; it < 12; ++it) {
        const size_t r = (size_t)(it * 64 + 2 * np);
        short8_t k0 = *(const short8_t*)(kptr + r * 2304 + g * 8);
        short8_t k1 = *(const short8_t*)(kptr + (r + 1) * 2304 + g * 8);
        short8_t v0 = *(const short8_t*)(vptr + r * 768 + g * 8);
        short8_t v1 = *(const short8_t*)(vptr + (r + 1) * 768 + g * 8);
        __syncthreads();
#pragma unroll
        for (int j = 0; j < 8; ++j) {
            const int d = g * 8 + j;
            const int e = d * 64 + ((2 * np) ^ (((d ^ (d >> 3)) & 7) << 3));
            *(unsigned int*)(kT + e) =
                (unsigned int)(unsigned short)k0[j] | ((unsigned int)(unsigned short)k1[j] << 16);
            *(unsigned int*)(vT + e) =
                (unsigned int)(unsigned short)v0[j] | ((unsigned int)(unsigned short)v1[j] << 16);
        }
        __syncthreads();
#pragma unroll
        for (int ks = 0; ks < 2; ++ks) {
            const int d = w * 16 + lr;
            short8_t a = *(const short8_t*)(kT + d * 64 +
                (((ks * 4 + lg) ^ ((d ^ (d >> 3)) & 7)) << 3));
#pragma unroll
            for (int nj = 0; nj < 4; ++nj) {
                const int e2 = nj * 16 + lr;
                short8_t bf = *(const short8_t*)(vT + e2 * 64 +
                    (((ks * 4 + lg) ^ ((e2 ^ (e2 >> 3)) & 7)) << 3));
                acc[nj] = __builtin_amdgcn_mfma_f32_16x16x32_bf16(a, bf, acc[nj], 0, 0, 0);
            }
        }
    }

    // gelu'd kv -> As [d:64][e:64] bf16, 8-chunk swizzled: chunk' = (e>>3) ^ (d&7)
    {
        const int drow = w * 16 + (lg << 2);
#pragma unroll
        for (int nj = 0; nj < 4; ++nj)
#pragma unroll
            for (int r = 0; r < 4; ++r) {
                const int d = drow + r;
                const int e = nj * 16 + lr;
                As[d * 64 + ((((e >> 3) ^ (d & 7)) << 3) | (e & 7))] =
                    to_bf16(gelu_f(acc[nj][r] * 0.125f));
            }
    }

    for (int ct = 0; ct < 3; ++ct) {
        const int c0 = ct * 256;
        short8_t rb[8];
#pragma unroll
        for (int i = 0; i < 8; ++i) {
            int ch = i * 256 + tid, row = ch >> 3, kc = ch & 7;
            rb[i] = *(const short8_t*)(wpT + (size_t)(c0 + row) * 768 + h * 64 + kc * 8);
        }
        __syncthreads();
#pragma unroll
        for (int i = 0; i < 8; ++i) {
            int ch = i * 256 + tid, row = ch >> 3, kc = ch & 7;
            *(short8_t*)(Bs + row * 64 + ((kc ^ (row & 7)) * 8)) = rb[i];
        }
        __syncthreads();

        f32x4_t acc2[4][4] = {};
#pragma unroll
        for (int ks = 0; ks < 2; ++ks) {
            short8_t a[4], bfr[4];
#pragma unroll
            for (int mi = 0; mi < 4; ++mi) {
                int row = mi * 16 + lr;
                a[mi] = *(const short8_t*)(As + row * 64 + (((ks * 4 + lg) ^ (row & 7)) * 8));
            }
#pragma unroll
            for (int nj = 0; nj < 4; ++nj) {
                int row = w * 64 + nj * 16 + lr;
                bfr[nj] = *(const short8_t*)(Bs + row * 64 + (((ks * 4 + lg) ^ (row & 7)) * 8));
            }
#pragma unroll
            for (int mi = 0; mi < 4; ++mi)
#pragma unroll
                for (int nj = 0; nj < 4; ++nj)
                    acc2[mi][nj] = __builtin_amdgcn_mfma_f32_16x16x32_bf16(a[mi], bfr[nj], acc2[mi][nj], 0, 0, 0);
        }
        __syncthreads();

#pragma unroll
        for (int mi = 0; mi < 4; ++mi)
#pragma unroll
            for (int nj = 0; nj < 4; ++nj) {
                unsigned int w0 = (unsigned int)to_bf16(acc2[mi][nj][0]) |
                                  ((unsigned int)to_bf16(acc2[mi][nj][1]) << 16);
                unsigned int w1 = (unsigned int)to_bf16(acc2[mi][nj][2]) |
                                  ((unsigned int)to_bf16(acc2[mi][nj][3]) << 16);
                uint2 pk; pk.x = w0; pk.y = w1;
                *(uint2*)(Bs + (w * 64 + nj * 16 + lr) * 64 + mi * 16 + lg * 4) = pk;
            }
        __syncthreads();
#pragma unroll
        for (int i = 0; i < 8; ++i) {
            int ch = i * 256 + tid, cl = ch >> 3, dk = ch & 7;
            short8_t v = *(const short8_t*)(Bs + cl * 64 + dk * 8);
            *(short8_t*)(MT + ((size_t)(b * 768) + c0 + cl) * 768 + h * 64 + dk * 8) = v;
        }
    }
}

extern "C" void kernel_launch(void* const* d_in, const int* in_sizes, int n_in,
                              void* d_out, int out_size, void* d_ws, size_t ws_size,
                              hipStream_t stream) {
    const float* x      = (const float*)d_in[0];
    const float* w_qkv  = (const float*)d_in[1];
    const float* w_proj = (const float*)d_in[2];
    const float* b_proj = (const float*)d_in[3];
    float* out = (float*)d_out;
    char* ws = (char*)d_ws;

    unsigned short* q_gelu  = (unsigned short*)(ws);               // 100,663,296
    unsigned short* wqkvT   = (unsigned short*)(ws + 100663296);   //   3,538,944
    unsigned short* wqkv_bf = (unsigned short*)(ws + 104202240);   //   3,538,944
    unsigned short* G_bf    = (unsigned short*)(ws + 107741184);   //  18,874,368
    unsigned short* T_bf    = (unsigned short*)(ws + 126615552);   //  18,874,368
    unsigned short* MT      = (unsigned short*)(ws + 145489920);   //  18,874,368
    unsigned short* xb   = (unsigned short*)d_out;                 // scratch in d_out
    unsigned short* wpT  = (unsigned short*)((char*)d_out + 136314880);

    // 1) merged prep: x->bf16, weight transposes, wqkv cvt
    k_prep<<<3632, 256, 0, stream>>>(x, w_qkv, w_proj, xb, wqkvT, wpT, wqkv_bf);
    // 2) GEMM1q: q_gelu = gelu(xb @ Wq^T)  [65536,768]
    k_gemm256<true, false, true, false><<<768, 512, 0, stream>>>(
        xb, 768, wqkvT, 768, q_gelu, 768, nullptr, 3, 768);
    // 3) G_b = x_b^T x_b (symmetric, 21 upper tiles per batch)
    k_G<<<336, 256, 0, stream>>>(xb, G_bf);
    // 4) T_b = G_b @ Wv
    k_gemm128<<<576, 256, 0, stream>>>(
        G_bf, 768, wqkvT + (size_t)1536 * 768, 768, T_bf, 768, 6, 768);
    // 5) kv_h + M fold
    k_kvM<<<192, 256, 0, stream>>>(wqkv_bf, T_bf, wpT, MT);
    // 6) GEMM2: out = q_gelu @ MT_b^T + b_proj
    k_gemm256<false, true, false, true><<<768, 512, 0, stream>>>(
        q_gelu, 768, MT, 768, out, 768, b_proj, 3, 768);
}